// Round 5
// baseline (131.019 us; speedup 1.0000x reference)
//
#include <hip/hip_runtime.h>
#include <math.h>

#define NV 3
#define NC 32
#define HS 256
#define WS 256
#define HT 128
#define WT 128
#define ND 48
#define NPIX (HT*WT)             // 16384
#define HSP 259                  // padded rows: y+1 for y in [-1, 257]
#define WSP 259
#define ROW4 (WSP*8)             // float4 per padded row = 2072
#define IMG4 (HSP*ROW4)          // float4 per padded view = 536648
#define FEAT_T_ELEMS (NV*IMG4*4) // floats
#define NB_INTERIOR (NV*HS)      // 768 blocks: one per (v,y)
#define NBORDER_PIX (3*(3*WSP + 3*HS))   // 4635 border pixels
#define NBORDER_F4  (NBORDER_PIX*8)      // 37080 float4
#define NB_BORDER   145                   // ceil(37080/256)

// ---- 4-lane (aligned group) cross-lane reductions via DPP (VALU pipe) ----
__device__ __forceinline__ float dpp_sum4(float x) {
    int v;
    v = __builtin_amdgcn_update_dpp(0, __float_as_int(x), 0xB1, 0xF, 0xF, true); // quad_perm xor1
    x += __int_as_float(v);
    v = __builtin_amdgcn_update_dpp(0, __float_as_int(x), 0x4E, 0xF, 0xF, true); // quad_perm xor2
    x += __int_as_float(v);
    return x;
}
__device__ __forceinline__ float dpp_max4(float x) {
    int v;
    v = __builtin_amdgcn_update_dpp(0, __float_as_int(x), 0xB1, 0xF, 0xF, true);
    x = fmaxf(x, __int_as_float(v));
    v = __builtin_amdgcn_update_dpp(0, __float_as_int(x), 0x4E, 0xF, 0xF, true);
    x = fmaxf(x, __int_as_float(v));
    return x;
}

// -------------------------------------------------------------------------
// Kernel A: (V,C,Hs,Ws) -> zero-padded (V,Hs+3,Ws+3,C) transpose + border
// zeroing + projection setup. Interior block = one (v,y) row.
// Lane = (q=tid&7, xl=tid>>3): store instr = 8 full consecutive 128B lines
// (perfect); load instr = 8 planes x 32B segments, sibling waves reuse the
// fetched lines via L1. No LDS, no barrier.
// -------------------------------------------------------------------------
__global__ __launch_bounds__(256) void prep(
        const float* __restrict__ src, float* __restrict__ dstf,
        const float* __restrict__ src_exts,
        const float* __restrict__ src_ints,
        const float* __restrict__ tar_exts,
        const float* __restrict__ tar_ints,
        float* __restrict__ proj_out) {
    float4* dst = (float4*)dstf;
    int bid = blockIdx.x;
    if (bid < NB_INTERIOR) {
        int v  = bid >> 8;
        int y  = bid & 255;
        int q  = threadIdx.x & 7;            // channel quad 0..7
        int xl = threadIdx.x >> 3;           // 0..31
        const float* in = src + ((size_t)(v*NC + q*4))*HS*WS + (size_t)y*WS;
        float4* drow = dst + (size_t)(v*HSP + y+1)*ROW4 + 8 + q;
        #pragma unroll
        for (int it = 0; it < 8; it++) {
            int x = it*32 + xl;
            float a = in[x];
            float b = in[HS*WS   + x];
            float c = in[2*HS*WS + x];
            float d = in[3*HS*WS + x];
            drow[x*8] = make_float4(a,b,c,d);
        }
        return;
    }
    // border zeroing
    int t = (bid - NB_INTERIOR)*256 + threadIdx.x;
    if (t < NBORDER_F4) {
        int pixb = t >> 3, q = t & 7;
        int v = pixb / (NBORDER_PIX/3);
        int r = pixb - v*(NBORDER_PIX/3);
        int y, x;
        if (r < 3*WSP) {                      // rows y=0,257,258 full width
            int band = r / WSP;
            y = (band == 0) ? 0 : (band == 1 ? 257 : 258);
            x = r - band*WSP;
        } else {                              // cols x=0,257,258, y=1..256
            int rr = r - 3*WSP;
            int band = rr >> 8;
            x = (band == 0) ? 0 : (band == 1 ? 257 : 258);
            y = 1 + (rr & 255);
        }
        dst[(v*HSP + y)*WSP*8 + x*8 + q] = make_float4(0.f,0.f,0.f,0.f);
    }
    // projection matrices: one thread, alongside border work
    if (bid == NB_INTERIOR && threadIdx.x == 0) {
        float Kt[9], Et[16];
        for (int i = 0; i < 9;  i++) Kt[i] = tar_ints[i];
        for (int i = 0; i < 16; i++) Et[i] = tar_exts[i];
        float T[12];
        for (int rI = 0; rI < 3; rI++)
            for (int col = 0; col < 4; col++) {
                float s = 0.f;
                for (int k = 0; k < 3; k++) s += Kt[rI*3+k] * Et[k*4+col];
                T[rI*4+col] = s;
            }
        float M[9]  = {T[0],T[1],T[2], T[4],T[5],T[6], T[8],T[9],T[10]};
        float tv[3] = {T[3],T[7],T[11]};
        float det = M[0]*(M[4]*M[8]-M[5]*M[7])
                  - M[1]*(M[3]*M[8]-M[5]*M[6])
                  + M[2]*(M[3]*M[7]-M[4]*M[6]);
        float id = 1.0f/det;
        float Mi[9];
        Mi[0] =  (M[4]*M[8]-M[5]*M[7])*id;
        Mi[1] = -(M[1]*M[8]-M[2]*M[7])*id;
        Mi[2] =  (M[1]*M[5]-M[2]*M[4])*id;
        Mi[3] = -(M[3]*M[8]-M[5]*M[6])*id;
        Mi[4] =  (M[0]*M[8]-M[2]*M[6])*id;
        Mi[5] = -(M[0]*M[5]-M[2]*M[3])*id;
        Mi[6] =  (M[3]*M[7]-M[4]*M[6])*id;
        Mi[7] = -(M[0]*M[7]-M[1]*M[6])*id;
        Mi[8] =  (M[0]*M[4]-M[1]*M[3])*id;
        float mt[3];
        for (int rI = 0; rI < 3; rI++)
            mt[rI] = -(Mi[rI*3+0]*tv[0] + Mi[rI*3+1]*tv[1] + Mi[rI*3+2]*tv[2]);
        float inv4[16] = {Mi[0],Mi[1],Mi[2],mt[0],
                          Mi[3],Mi[4],Mi[5],mt[1],
                          Mi[6],Mi[7],Mi[8],mt[2],
                          0.f,0.f,0.f,1.f};
        for (int v = 0; v < NV; v++) {
            const float* Ks = src_ints + v*9;
            const float* Ev = src_exts + v*16;
            float P34[12];
            for (int rI = 0; rI < 3; rI++)
                for (int col = 0; col < 4; col++) {
                    float s = 0.f;
                    for (int k = 0; k < 3; k++) s += Ks[rI*3+k] * Ev[k*4+col];
                    P34[rI*4+col] = s;
                }
            for (int rI = 0; rI < 3; rI++)
                for (int col = 0; col < 4; col++) {
                    float s = 0.f;
                    for (int k = 0; k < 4; k++) s += P34[rI*4+k] * inv4[k*4+col];
                    proj_out[v*12 + rI*4 + col] = s;
                }
        }
    }
}

// -------------------------------------------------------------------------
// Kernel B: fused plane-sweep + variance cost + softmax + depth/CI.
// Block = 16 pixels, 4 waves; wave w owns 12 depths. Lane = p*4+q:
// p = pixel (0..15), q = channel octet (8 channels = 2 float4 per tap).
// Scalar projection math amortized over 16 px/wave; rcp approx for 1/z.
// XCD-swizzled blocks; DPP 4-lane reductions; LDS meet + wave-0 softmax.
// -------------------------------------------------------------------------
__global__ __launch_bounds__(256, 4) void depth_main(
        const float4* __restrict__ featT,
        const float* __restrict__ proj,
        const float* __restrict__ near_far,
        float* __restrict__ out) {
    __shared__ float cl[16][52];

    const int tid  = threadIdx.x;
    const int w    = tid >> 6;       // wave -> depth slice
    const int lane = tid & 63;
    const int p    = lane >> 2;      // pixel within block (0..15)
    const int q    = lane & 3;       // channel octet

    // XCD swizzle: 1024 blocks, XCD k owns logical [k*128, k*128+128)
    const int lb  = ((blockIdx.x & 7) << 7) | (blockIdx.x >> 3);
    const int pix = lb*16 + p;
    const float cx = (pix & (WT-1)) + 0.5f;
    const float cy = (pix >> 7) + 0.5f;

    float rx[NV], ry[NV], rz[NV], tx[NV], ty[NV], tz[NV];
    #pragma unroll
    for (int v = 0; v < NV; v++) {
        const float* P = proj + v*12;
        rx[v] = P[0]*cx + P[1]*cy + P[2];  tx[v] = P[3];
        ry[v] = P[4]*cx + P[5]*cy + P[6];  ty[v] = P[7];
        rz[v] = P[8]*cx + P[9]*cy + P[10]; tz[v] = P[11];
    }

    const float nearv = near_far[pix];
    const float farv  = near_far[NPIX + pix];
    const float step  = (farv - nearv) * (1.0f/(ND-1));
    const float d0    = (float)(w*12);

    // lane base: fold padded +1 row/col and the 2q channel offset
    const float4* baseL = featT + (ROW4 + 8) + 2*q;

    #pragma unroll 2
    for (int dd = 0; dd < 12; dd++) {
        const float dv = fmaf(step, d0 + (float)dd, nearv);
        float a0=0.f,a1=0.f,a2=0.f,a3=0.f,a4=0.f,a5=0.f,a6=0.f,a7=0.f;
        float m0=0.f,m1=0.f,m2_=0.f,m3=0.f,m4=0.f,m5=0.f,m6=0.f,m7=0.f;
        #pragma unroll
        for (int v = 0; v < NV; v++) {
            float pxx = fmaf(rx[v], dv, tx[v]);
            float pyy = fmaf(ry[v], dv, ty[v]);
            float pzz = fmaf(rz[v], dv, tz[v]);
            float invz = __builtin_amdgcn_rcpf(fmaxf(pzz, 1e-6f));
            float sx = fminf(fmaxf(fmaf(pxx, invz, -0.5f), -1.0f), 256.0f);
            float sy = fminf(fmaxf(fmaf(pyy, invz, -0.5f), -1.0f), 256.0f);
            float x0f = floorf(sx), y0f = floorf(sy);
            float wx = sx - x0f,   wy = sy - y0f;
            int xi = (int)x0f;               // -1..256
            int yi = (int)y0f;               // -1..256
            int r0 = v*IMG4 + yi*ROW4 + xi*8;
            int r1 = r0 + ROW4;
            float4 fa00 = baseL[r0];
            float4 fb00 = baseL[r0 + 1];
            float4 fa01 = baseL[r0 + 8];
            float4 fb01 = baseL[r0 + 9];
            float4 fa10 = baseL[r1];
            float4 fb10 = baseL[r1 + 1];
            float4 fa11 = baseL[r1 + 8];
            float4 fb11 = baseL[r1 + 9];
            float w11 = wx*wy;
            float w10 = wy - w11;
            float w01 = wx - w11;
            float w00 = (1.0f - wx) - w10;
            float v0 = fa00.x*w00 + fa01.x*w01 + fa10.x*w10 + fa11.x*w11;
            float v1 = fa00.y*w00 + fa01.y*w01 + fa10.y*w10 + fa11.y*w11;
            float v2 = fa00.z*w00 + fa01.z*w01 + fa10.z*w10 + fa11.z*w11;
            float v3 = fa00.w*w00 + fa01.w*w01 + fa10.w*w10 + fa11.w*w11;
            float v4 = fb00.x*w00 + fb01.x*w01 + fb10.x*w10 + fb11.x*w11;
            float v5 = fb00.y*w00 + fb01.y*w01 + fb10.y*w10 + fb11.y*w11;
            float v6 = fb00.z*w00 + fb01.z*w01 + fb10.z*w10 + fb11.z*w11;
            float v7 = fb00.w*w00 + fb01.w*w01 + fb10.w*w10 + fb11.w*w11;
            a0 = fmaf(v0,v0,a0); a1 = fmaf(v1,v1,a1);
            a2 = fmaf(v2,v2,a2); a3 = fmaf(v3,v3,a3);
            a4 = fmaf(v4,v4,a4); a5 = fmaf(v5,v5,a5);
            a6 = fmaf(v6,v6,a6); a7 = fmaf(v7,v7,a7);
            m0 += v0; m1 += v1; m2_ += v2; m3 += v3;
            m4 += v4; m5 += v5; m6  += v6; m7 += v7;
        }
        float a  = ((a0+a1)+(a2+a3)) + ((a4+a5)+(a6+a7));
        float m2 = ((m0*m0 + m1*m1) + (m2_*m2_ + m3*m3))
                 + ((m4*m4 + m5*m5) + (m6*m6 + m7*m7));
        a  = dpp_sum4(a);
        m2 = dpp_sum4(m2);
        float cost = (a*(1.0f/3.0f) - m2*(1.0f/9.0f)) * (1.0f/32.0f);
        if (q == 0) cl[p][w*12 + dd] = cost;
    }

    __syncthreads();
    if (w != 0) return;

    // softmax over 48 depths: lane q holds depths q*12..q*12+11
    float n[12], e[12];
    #pragma unroll
    for (int j = 0; j < 12; j++) n[j] = -cl[p][q*12 + j];
    float mx = n[0];
    #pragma unroll
    for (int j = 1; j < 12; j++) mx = fmaxf(mx, n[j]);
    mx = dpp_max4(mx);
    float s0 = 0.f, s1 = 0.f;
    #pragma unroll
    for (int j = 0; j < 12; j++) {
        float dvj = fmaf(step, (float)(q*12 + j), nearv);
        e[j] = __expf(n[j] - mx);
        s0 += e[j];
        s1 = fmaf(e[j], dvj, s1);
    }
    s0 = dpp_sum4(s0);
    s1 = dpp_sum4(s1);
    float depth = s1 / s0;
    float s2 = 0.f;
    #pragma unroll
    for (int j = 0; j < 12; j++) {
        float qd = fmaf(step, (float)(q*12 + j), nearv) - depth;
        s2 = fmaf(e[j]*qd, qd, s2);
    }
    s2 = dpp_sum4(s2);
    float var = s2 / s0;
    float hci = sqrtf(fmaxf(var, 1e-12f));
    if (q == 0) {
        out[pix]          = depth;
        out[NPIX + pix]   = fmaxf(depth - hci, nearv);
        out[2*NPIX + pix] = fminf(depth + hci, farv);
    }
}

// -------------------------------------------------------------------------
extern "C" void kernel_launch(void* const* d_in, const int* in_sizes, int n_in,
                              void* d_out, int out_size, void* d_ws, size_t ws_size,
                              hipStream_t stream) {
    const float* src_feat = (const float*)d_in[0];
    const float* src_exts = (const float*)d_in[1];
    const float* src_ints = (const float*)d_in[2];
    const float* tar_exts = (const float*)d_in[3];
    const float* tar_ints = (const float*)d_in[4];
    const float* near_far = (const float*)d_in[5];
    float* out   = (float*)d_out;
    float* featT = (float*)d_ws;                 // 25.8 MB padded transposed
    float* proj  = featT + FEAT_T_ELEMS;         // 36 floats

    hipLaunchKernelGGL(prep, dim3(NB_INTERIOR + NB_BORDER), dim3(256), 0, stream,
                       src_feat, featT, src_exts, src_ints, tar_exts, tar_ints, proj);
    hipLaunchKernelGGL(depth_main, dim3(NPIX/16), dim3(256), 0, stream,
                       (const float4*)featT, proj, near_far, out);
}

// Round 6
// 120.070 us; speedup vs baseline: 1.0912x; 1.0912x over previous
//
#include <hip/hip_runtime.h>
#include <math.h>

#define NV 3
#define NC 32
#define HS 256
#define WS 256
#define HT 128
#define WT 128
#define ND 48
#define NPIX (HT*WT)             // 16384
#define HSP 259                  // padded rows: y+1 for y in [-1, 257]
#define WSP 259
#define ROW4 (WSP*8)             // float4 per padded row = 2072
#define IMG4 (HSP*ROW4)          // float4 per padded view = 536648
#define FEAT_T_ELEMS (NV*IMG4*4) // floats
#define NB_INTERIOR (NV*HS)      // 768 blocks: one per (v,y)
#define NBORDER_PIX (3*(3*WSP + 3*HS))   // 4635 border pixels
#define NBORDER_F4  (NBORDER_PIX*8)      // 37080 float4
#define NB_BORDER   145                   // ceil(37080/256)

// ---- 8-lane (aligned group) cross-lane reductions via DPP (VALU pipe) ----
__device__ __forceinline__ float dpp_sum8(float x) {
    int v;
    v = __builtin_amdgcn_update_dpp(0, __float_as_int(x), 0xB1,  0xF, 0xF, true); // quad_perm xor1
    x += __int_as_float(v);
    v = __builtin_amdgcn_update_dpp(0, __float_as_int(x), 0x4E,  0xF, 0xF, true); // quad_perm xor2
    x += __int_as_float(v);
    v = __builtin_amdgcn_update_dpp(0, __float_as_int(x), 0x141, 0xF, 0xF, true); // row_half_mirror
    x += __int_as_float(v);
    return x;
}
__device__ __forceinline__ float dpp_max8(float x) {
    int v;
    v = __builtin_amdgcn_update_dpp(0, __float_as_int(x), 0xB1,  0xF, 0xF, true);
    x = fmaxf(x, __int_as_float(v));
    v = __builtin_amdgcn_update_dpp(0, __float_as_int(x), 0x4E,  0xF, 0xF, true);
    x = fmaxf(x, __int_as_float(v));
    v = __builtin_amdgcn_update_dpp(0, __float_as_int(x), 0x141, 0xF, 0xF, true);
    x = fmaxf(x, __int_as_float(v));
    return x;
}

// component-wise float4 helpers (eligible for v_pk_fma_f32 packing)
__device__ __forceinline__ float4 f4mul(float4 a, float s) {
    return make_float4(a.x*s, a.y*s, a.z*s, a.w*s);
}
__device__ __forceinline__ float4 f4fma(float4 a, float s, float4 c) {
    return make_float4(fmaf(a.x,s,c.x), fmaf(a.y,s,c.y),
                       fmaf(a.z,s,c.z), fmaf(a.w,s,c.w));
}
__device__ __forceinline__ float4 f4fma2(float4 a, float4 c) {   // c += a*a
    return make_float4(fmaf(a.x,a.x,c.x), fmaf(a.y,a.y,c.y),
                       fmaf(a.z,a.z,c.z), fmaf(a.w,a.w,c.w));
}
__device__ __forceinline__ float4 f4add(float4 a, float4 b) {
    return make_float4(a.x+b.x, a.y+b.y, a.z+b.z, a.w+b.w);
}

// -------------------------------------------------------------------------
// Kernel A: (V,C,Hs,Ws) -> zero-padded (V,Hs+3,Ws+3,C) transpose + border
// zeroing + projection setup. Interior block = one (v,y) row; thread
// (q=tid&7, xg=tid>>3) does a register 4x4 transpose of 4 plane-float4s.
// Per wave-instr: loads = 8 full 128B lines, stores = 8 full 128B lines.
// -------------------------------------------------------------------------
__global__ __launch_bounds__(256) void prep(
        const float* __restrict__ src, float* __restrict__ dstf,
        const float* __restrict__ src_exts,
        const float* __restrict__ src_ints,
        const float* __restrict__ tar_exts,
        const float* __restrict__ tar_ints,
        float* __restrict__ proj_out) {
    float4* dst = (float4*)dstf;
    int bid = blockIdx.x;
    if (bid < NB_INTERIOR) {
        int v  = bid >> 8;
        int y  = bid & 255;
        int q  = threadIdx.x & 7;            // channel quad 0..7
        int xg = threadIdx.x >> 3;           // 0..31
        const float* in = src + ((size_t)(v*NC + q*4))*HS*WS + (size_t)y*WS;
        float4* drow = dst + (size_t)(v*HSP + y+1)*ROW4 + 8 + q;
        #pragma unroll
        for (int half = 0; half < 2; half++) {
            int x0 = (xg + half*32)*4;
            float4 p0 = *(const float4*)(in + x0);
            float4 p1 = *(const float4*)(in + HS*WS   + x0);
            float4 p2 = *(const float4*)(in + 2*HS*WS + x0);
            float4 p3 = *(const float4*)(in + 3*HS*WS + x0);
            drow[(x0+0)*8] = make_float4(p0.x, p1.x, p2.x, p3.x);
            drow[(x0+1)*8] = make_float4(p0.y, p1.y, p2.y, p3.y);
            drow[(x0+2)*8] = make_float4(p0.z, p1.z, p2.z, p3.z);
            drow[(x0+3)*8] = make_float4(p0.w, p1.w, p2.w, p3.w);
        }
        return;
    }
    // border zeroing
    int t = (bid - NB_INTERIOR)*256 + threadIdx.x;
    if (t < NBORDER_F4) {
        int pixb = t >> 3, q = t & 7;
        int v = pixb / (NBORDER_PIX/3);
        int r = pixb - v*(NBORDER_PIX/3);
        int y, x;
        if (r < 3*WSP) {                      // rows y=0,257,258 full width
            int band = r / WSP;
            y = (band == 0) ? 0 : (band == 1 ? 257 : 258);
            x = r - band*WSP;
        } else {                              // cols x=0,257,258, y=1..256
            int rr = r - 3*WSP;
            int band = rr >> 8;
            x = (band == 0) ? 0 : (band == 1 ? 257 : 258);
            y = 1 + (rr & 255);
        }
        dst[(v*HSP + y)*WSP*8 + x*8 + q] = make_float4(0.f,0.f,0.f,0.f);
    }
    // projection matrices: one thread, alongside border work
    if (bid == NB_INTERIOR && threadIdx.x == 0) {
        float Kt[9], Et[16];
        for (int i = 0; i < 9;  i++) Kt[i] = tar_ints[i];
        for (int i = 0; i < 16; i++) Et[i] = tar_exts[i];
        float T[12];
        for (int rI = 0; rI < 3; rI++)
            for (int col = 0; col < 4; col++) {
                float s = 0.f;
                for (int k = 0; k < 3; k++) s += Kt[rI*3+k] * Et[k*4+col];
                T[rI*4+col] = s;
            }
        float M[9]  = {T[0],T[1],T[2], T[4],T[5],T[6], T[8],T[9],T[10]};
        float tv[3] = {T[3],T[7],T[11]};
        float det = M[0]*(M[4]*M[8]-M[5]*M[7])
                  - M[1]*(M[3]*M[8]-M[5]*M[6])
                  + M[2]*(M[3]*M[7]-M[4]*M[6]);
        float id = 1.0f/det;
        float Mi[9];
        Mi[0] =  (M[4]*M[8]-M[5]*M[7])*id;
        Mi[1] = -(M[1]*M[8]-M[2]*M[7])*id;
        Mi[2] =  (M[1]*M[5]-M[2]*M[4])*id;
        Mi[3] = -(M[3]*M[8]-M[5]*M[6])*id;
        Mi[4] =  (M[0]*M[8]-M[2]*M[6])*id;
        Mi[5] = -(M[0]*M[5]-M[2]*M[3])*id;
        Mi[6] =  (M[3]*M[7]-M[4]*M[6])*id;
        Mi[7] = -(M[0]*M[7]-M[1]*M[6])*id;
        Mi[8] =  (M[0]*M[4]-M[1]*M[3])*id;
        float mt[3];
        for (int rI = 0; rI < 3; rI++)
            mt[rI] = -(Mi[rI*3+0]*tv[0] + Mi[rI*3+1]*tv[1] + Mi[rI*3+2]*tv[2]);
        float inv4[16] = {Mi[0],Mi[1],Mi[2],mt[0],
                          Mi[3],Mi[4],Mi[5],mt[1],
                          Mi[6],Mi[7],Mi[8],mt[2],
                          0.f,0.f,0.f,1.f};
        for (int v = 0; v < NV; v++) {
            const float* Ks = src_ints + v*9;
            const float* Ev = src_exts + v*16;
            float P34[12];
            for (int rI = 0; rI < 3; rI++)
                for (int col = 0; col < 4; col++) {
                    float s = 0.f;
                    for (int k = 0; k < 3; k++) s += Ks[rI*3+k] * Ev[k*4+col];
                    P34[rI*4+col] = s;
                }
            for (int rI = 0; rI < 3; rI++)
                for (int col = 0; col < 4; col++) {
                    float s = 0.f;
                    for (int k = 0; k < 4; k++) s += P34[rI*4+k] * inv4[k*4+col];
                    proj_out[v*12 + rI*4 + col] = s;
                }
        }
    }
}

// -------------------------------------------------------------------------
// Kernel B: fused plane-sweep + variance cost + softmax + depth/CI.
// r4 shape: block = 8 pixels, 4 waves; wave w owns 12 depths; lane = p*8+q
// (q = channel quad, one float4 per tap -> low VGPR pressure).
// rcpf for 1/z; padded-coord fold (+0.5 -> +1 shift baked into clamp range)
// gives a single non-negative u32 index -> saddr loads with imm offsets.
// float4 component math for v_pk_fma_f32 packing. XCD swizzle. DPP reduce.
// -------------------------------------------------------------------------
__global__ __launch_bounds__(256, 6) void depth_main(
        const float4* __restrict__ featT,
        const float* __restrict__ proj,
        const float* __restrict__ near_far,
        float* __restrict__ out) {
    __shared__ float cl[8][56];

    const int tid  = threadIdx.x;
    const int w    = tid >> 6;       // wave -> depth slice
    const int lane = tid & 63;
    const int p    = lane >> 3;      // pixel within block (0..7)
    const int q    = lane & 7;       // channel quad

    // XCD swizzle: 2048 blocks, XCD k owns logical [k*256, k*256+256)
    const int lb  = ((blockIdx.x & 7) << 8) | (blockIdx.x >> 3);
    const int pix = lb*8 + p;
    const float cx = (pix & (WT-1)) + 0.5f;
    const float cy = (pix >> 7) + 0.5f;

    float rx[NV], ry[NV], rz[NV], tx[NV], ty[NV], tz[NV];
    #pragma unroll
    for (int v = 0; v < NV; v++) {
        const float* P = proj + v*12;
        rx[v] = P[0]*cx + P[1]*cy + P[2];  tx[v] = P[3];
        ry[v] = P[4]*cx + P[5]*cy + P[6];  ty[v] = P[7];
        rz[v] = P[8]*cx + P[9]*cy + P[10]; tz[v] = P[11];
    }

    const float nearv = near_far[pix];
    const float farv  = near_far[NPIX + pix];
    const float step  = (farv - nearv) * (1.0f/(ND-1));
    const float d0    = (float)(w*12);

    #pragma unroll 2
    for (int dd = 0; dd < 12; dd++) {
        const float dv = fmaf(step, d0 + (float)dd, nearv);
        float4 a4 = make_float4(0.f,0.f,0.f,0.f);
        float4 m4 = make_float4(0.f,0.f,0.f,0.f);
        #pragma unroll
        for (int v = 0; v < NV; v++) {
            float pxx = fmaf(rx[v], dv, tx[v]);
            float pyy = fmaf(ry[v], dv, ty[v]);
            float pzz = fmaf(rz[v], dv, tz[v]);
            float invz = __builtin_amdgcn_rcpf(fmaxf(pzz, 1e-6f));
            // padded coords: sp = s_unpadded + 1, range [0, 257]
            float sxp = fminf(fmaxf(fmaf(pxx, invz, 0.5f), 0.0f), 257.0f);
            float syp = fminf(fmaxf(fmaf(pyy, invz, 0.5f), 0.0f), 257.0f);
            float x0f = floorf(sxp), y0f = floorf(syp);
            float wx = sxp - x0f,   wy = syp - y0f;
            unsigned xi = (unsigned)(int)x0f;     // 0..257
            unsigned yi = (unsigned)(int)y0f;     // 0..257
            unsigned idx = (unsigned)(v*IMG4) + yi*ROW4 + xi*8u + (unsigned)q;
            float4 f00 = featT[idx];
            float4 f01 = featT[idx + 8];
            float4 f10 = featT[idx + ROW4];
            float4 f11 = featT[idx + ROW4 + 8];
            float w11 = wx*wy;
            float w10 = wy - w11;
            float w01 = wx - w11;
            float w00 = (1.0f - wx) - w10;
            float4 val = f4fma(f11, w11, f4fma(f10, w10,
                         f4fma(f01, w01, f4mul(f00, w00))));
            a4 = f4fma2(val, a4);
            m4 = f4add(m4, val);
        }
        float a  = (a4.x + a4.y) + (a4.z + a4.w);
        float m2 = (m4.x*m4.x + m4.y*m4.y) + (m4.z*m4.z + m4.w*m4.w);
        a  = dpp_sum8(a);
        m2 = dpp_sum8(m2);
        float cost = (a*(1.0f/3.0f) - m2*(1.0f/9.0f)) * (1.0f/32.0f);
        if (q == 0) cl[p][w*12 + dd] = cost;
    }

    __syncthreads();
    if (w != 0) return;

    // softmax over 48 depths: lane q holds depths q, q+8, ..., q+40
    float n[6], e[6];
    #pragma unroll
    for (int j = 0; j < 6; j++) n[j] = -cl[p][q + 8*j];
    float mx = n[0];
    #pragma unroll
    for (int j = 1; j < 6; j++) mx = fmaxf(mx, n[j]);
    mx = dpp_max8(mx);
    float s0 = 0.f, s1 = 0.f;
    #pragma unroll
    for (int j = 0; j < 6; j++) {
        float dvj = fmaf(step, (float)(q + 8*j), nearv);
        e[j] = __expf(n[j] - mx);
        s0 += e[j];
        s1 = fmaf(e[j], dvj, s1);
    }
    s0 = dpp_sum8(s0);
    s1 = dpp_sum8(s1);
    float depth = s1 / s0;
    float s2 = 0.f;
    #pragma unroll
    for (int j = 0; j < 6; j++) {
        float qd = fmaf(step, (float)(q + 8*j), nearv) - depth;
        s2 = fmaf(e[j]*qd, qd, s2);
    }
    s2 = dpp_sum8(s2);
    float var = s2 / s0;
    float hci = sqrtf(fmaxf(var, 1e-12f));
    if (q == 0) {
        out[pix]          = depth;
        out[NPIX + pix]   = fmaxf(depth - hci, nearv);
        out[2*NPIX + pix] = fminf(depth + hci, farv);
    }
}

// -------------------------------------------------------------------------
extern "C" void kernel_launch(void* const* d_in, const int* in_sizes, int n_in,
                              void* d_out, int out_size, void* d_ws, size_t ws_size,
                              hipStream_t stream) {
    const float* src_feat = (const float*)d_in[0];
    const float* src_exts = (const float*)d_in[1];
    const float* src_ints = (const float*)d_in[2];
    const float* tar_exts = (const float*)d_in[3];
    const float* tar_ints = (const float*)d_in[4];
    const float* near_far = (const float*)d_in[5];
    float* out   = (float*)d_out;
    float* featT = (float*)d_ws;                 // 25.8 MB padded transposed
    float* proj  = featT + FEAT_T_ELEMS;         // 36 floats

    hipLaunchKernelGGL(prep, dim3(NB_INTERIOR + NB_BORDER), dim3(256), 0, stream,
                       src_feat, featT, src_exts, src_ints, tar_exts, tar_ints, proj);
    hipLaunchKernelGGL(depth_main, dim3(NPIX/8), dim3(256), 0, stream,
                       (const float4*)featT, proj, near_far, out);
}